// Round 7
// baseline (239.616 us; speedup 1.0000x reference)
//
#include <hip/hip_runtime.h>
#include <hip/hip_bf16.h>

// Problem constants
#define NND 50000      // nodes
#define NED 800000     // edges (without self-loops)
#define INC 10
#define HID 96
#define OUTC 48
#define NOUT (NND*OUTC)
#define NBLK 196       // ceil(NND/256)
#define MTILES 3125    // 50000 / 16
#define NPART 8        // XCD partitions for the scatter
#define PART_NODES 6250
#define SCAT_BPP 64    // blocks per partition

typedef __hip_bfloat16 bf16;
typedef __attribute__((ext_vector_type(8))) short short8;
typedef __attribute__((ext_vector_type(4))) float f32x4;

// ---- workspace layout ----
// [0,16): flags.  Float region (offsets in floats from F):
#define XF_O   0L                 // 500000  (x: N x 10)
#define W1F_O  500000L            // 960   (W1 then b1 contiguous: 1056)
#define B1F_O  500960L            // 96
#define WMF_O  501056L            // 4608  (fp32 copy; heads use bf16 wct)
#define BMF_O  505664L            // 48
#define WLF_O  505712L            // 4608
#define BLF_O  510320L            // 48
#define DIS_O  510368L            // 50000 (rsqrt(deg+1))
#define FLOATS_TOT 560368L
// after floats: h   [NND*96] ushort (bf16)
//               wct [96*96]  ushort (bf16) WcatT[n][k]; n<48 = W_mu col, n>=48 = W_ls col
//               v   [NND*96] ushort (bf16) aggregated hidden
// int region after v (intBase is 16B-aligned):
#define CNT_IO   0L               // 50000
#define START_IO 50000L           // 50001 (+1 pad -> 100002)
#define CUR_IO   100002L          // 50000
#define BS_IO    150002L          // 256
#define BOFF_IO  150258L          // 256 + pad -> 150528 (16B aligned)
#define PK_IO    150528L          // 800000 u32 packed {row | col<<16}
#define EDGE_IO  950528L          // 800000 u32 CSR records (src)

__device__ __forceinline__ float b2f(bf16 v) { return __bfloat162float(v); }
__device__ __forceinline__ float bfLo(unsigned int p) { return __uint_as_float(p << 16); }
__device__ __forceinline__ float bfHi(unsigned int p) { return __uint_as_float(p & 0xffff0000u); }
__device__ __forceinline__ unsigned short f2bu(float v) {
    return __bfloat16_as_ushort(__float2bfloat16(v));
}

// K0: runtime dtype sniffer (deterministic every call)
__global__ __launch_bounds__(256) void k_sniff(const int* ei, const unsigned short* xs, int* flags) {
    __shared__ int s_oddnz, s_big;
    if (threadIdx.x == 0) { s_oddnz = 0; s_big = 0; }
    __syncthreads();
    int t = threadIdx.x;
    if (t < 128) {
        if (ei[2 * t + 1] != 0) atomicOr(&s_oddnz, 1);
    }
    for (int k = 0; k < 8; ++k) {
        unsigned short u = xs[t * 8 + k];
        float f = __uint_as_float(((unsigned int)u) << 16);
        if (!(fabsf(f) < 64.0f)) atomicOr(&s_big, 1);
    }
    __syncthreads();
    if (threadIdx.x == 0) {
        flags[0] = (s_oddnz == 0) ? 1 : 0;  // iw: 1 = int64
        flags[1] = s_big ? 1 : 0;           // ff: 1 = fp32
    }
}

// K1: fused convert-to-fp32 + bf16 transposed head-weight build
//     + edge pack (row|col<<16) + degree count
#define CVT_TOT 510368
#define DEG_THREADS 200000
__global__ __launch_bounds__(256) void k_prep(const void* x, const void* w1, const void* b1,
                                              const void* wm, const void* bm,
                                              const void* wl, const void* bl,
                                              const int* ei, const int* flags,
                                              float* F, unsigned short* wct,
                                              unsigned int* pk, int* cnt) {
    int idx = blockIdx.x * 256 + threadIdx.x;
    if (idx < CVT_TOT) {
        int ff = flags[1];
        const void* src; long off;
        if      (idx < 500000) { src = x;  off = idx; }
        else if (idx < 500960) { src = w1; off = idx - 500000; }
        else if (idx < 501056) { src = b1; off = idx - 500960; }
        else if (idx < 505664) { src = wm; off = idx - 501056; }
        else if (idx < 505712) { src = bm; off = idx - 505664; }
        else if (idx < 510320) { src = wl; off = idx - 505712; }
        else                   { src = bl; off = idx - 510320; }
        float v = ff ? ((const float*)src)[off] : b2f(((const bf16*)src)[off]);
        F[idx] = v;
        if (idx >= 501056 && idx < 505664) {          // W_mu[k][j] -> wct[j][k]
            long rel = idx - 501056;
            wct[(rel % OUTC) * (long)HID + rel / OUTC] = f2bu(v);
        } else if (idx >= 505712 && idx < 510320) {   // W_ls[k][j] -> wct[48+j][k]
            long rel = idx - 505712;
            wct[(OUTC + rel % OUTC) * (long)HID + rel / OUTC] = f2bu(v);
        }
    } else if (idx < CVT_TOT + DEG_THREADS) {
        int j = idx - CVT_TOT;   // 4 edges per thread
        int r0, r1, r2, r3, c0, c1, c2, c3;
        if (flags[0]) {
            const int4* pr = (const int4*)ei;
            const int4* pc = (const int4*)(ei + 2L * NED);
            int4 ra = pr[2 * j], rb = pr[2 * j + 1];
            int4 ca = pc[2 * j], cb = pc[2 * j + 1];
            r0 = ra.x; r1 = ra.z; r2 = rb.x; r3 = rb.z;
            c0 = ca.x; c1 = ca.z; c2 = cb.x; c3 = cb.z;
        } else {
            int4 ra = ((const int4*)ei)[j];
            int4 ca = ((const int4*)(ei + NED))[j];
            r0 = ra.x; r1 = ra.y; r2 = ra.z; r3 = ra.w;
            c0 = ca.x; c1 = ca.y; c2 = ca.z; c3 = ca.w;
        }
        uint4 out;
        out.x = (unsigned)r0 | ((unsigned)c0 << 16);
        out.y = (unsigned)r1 | ((unsigned)c1 << 16);
        out.z = (unsigned)r2 | ((unsigned)c2 << 16);
        out.w = (unsigned)r3 | ((unsigned)c3 << 16);
        ((uint4*)pk)[j] = out;
        atomicAdd(&cnt[c0], 1); atomicAdd(&cnt[c1], 1);
        atomicAdd(&cnt[c2], 1); atomicAdd(&cnt[c3], 1);
    }
}

// K2a: per-block sums of cnt (wave shuffle reduce)
__global__ __launch_bounds__(256) void k_bsum(const int* cnt, int* bsum) {
    int i = blockIdx.x * 256 + threadIdx.x;
    int v = (i < NND) ? cnt[i] : 0;
#pragma unroll
    for (int off = 32; off >= 1; off >>= 1) v += __shfl_down(v, off, 64);
    __shared__ int ws[4];
    int wid = threadIdx.x >> 6, lane = threadIdx.x & 63;
    if (lane == 0) ws[wid] = v;
    __syncthreads();
    if (threadIdx.x == 0) bsum[blockIdx.x] = ws[0] + ws[1] + ws[2] + ws[3];
}

// K2b: single small block scans the 196 block sums -> exclusive offsets
__global__ __launch_bounds__(256) void k_scan2(const int* bsum, int* boff) {
    __shared__ int lds[256];
    int tid = threadIdx.x;
    int v = (tid < NBLK) ? bsum[tid] : 0;
    lds[tid] = v;
    __syncthreads();
    int incl = v;
    for (int off = 1; off < 256; off <<= 1) {
        int t = (tid >= off) ? lds[tid - off] : 0;
        __syncthreads();
        incl += t; lds[tid] = incl;
        __syncthreads();
    }
    if (tid < NBLK) boff[tid] = incl - v;
}

// K2c: block-local exclusive scan + offset -> start/cursor; dis=rsqrt(deg+1)
__global__ __launch_bounds__(256) void k_fill(const int* cnt, const int* boff,
                                              int* start, int* cursor, float* F) {
    __shared__ int lds[256];
    int tid = threadIdx.x;
    int i = blockIdx.x * 256 + tid;
    int c = (i < NND) ? cnt[i] : 0;
    lds[tid] = c;
    __syncthreads();
    int incl = c;
    for (int off = 1; off < 256; off <<= 1) {
        int t = (tid >= off) ? lds[tid - off] : 0;
        __syncthreads();
        incl += t; lds[tid] = incl;
        __syncthreads();
    }
    int run = boff[blockIdx.x] + incl - c;
    if (i <= NND) start[i] = run;        // i==NND lands here -> total == NED
    if (i < NND) {
        cursor[i] = run;
        F[DIS_O + i] = rsqrtf((float)c + 1.0f);
    }
}

// K3: XCD-partitioned scatter. Block b owns dest range [ (b&7)*6250, +6250 ).
// The 64 blocks per partition sweep the packed stream; only in-range edges
// are committed -> every edges[]/cursor[] line written by ONE XCD only.
__global__ __launch_bounds__(256) void k_scatter(const unsigned int* pk, int* cursor,
                                                 unsigned int* edges) {
    int p = blockIdx.x & (NPART - 1);
    int bi = blockIdx.x >> 3;                 // 0..63
    unsigned int lo = (unsigned)p * PART_NODES;
    int tid = bi * 256 + threadIdx.x;         // 0..16383
    const uint4* pk4 = (const uint4*)pk;
    for (int g = tid; g < NED / 4; g += SCAT_BPP * 256) {
        uint4 e = pk4[g];
#pragma unroll
        for (int q = 0; q < 4; ++q) {
            unsigned int w = (q == 0) ? e.x : (q == 1) ? e.y : (q == 2) ? e.z : e.w;
            unsigned int c = w >> 16;
            if (c - lo < PART_NODES) {
                int pos = atomicAdd(&cursor[c], 1);
                edges[pos] = w & 0xffffu;     // src only; norm recomputed by consumers
            }
        }
    }
}

// K4: fused layer1 — FOUR threads per node (quad in-wave): each takes every
// 4th edge, butterfly-combines the 10 partials, then emits 24 of 96 h feats.
__global__ __launch_bounds__(256) void k_layer1(const int* start, const unsigned int* edges,
                                                const float* F, unsigned short* h) {
    __shared__ float w1s[1056];   // W1 (960) then b1 (96), contiguous in F
    for (int i = threadIdx.x; i < 1056; i += 256) w1s[i] = F[W1F_O + i];
    __syncthreads();
    int idx = blockIdx.x * 256 + threadIdx.x;
    if (idx >= NND * 4) return;
    int node = idx >> 2, sub = idx & 3;
    float dn = F[DIS_O + node];
    float ax[INC];
#pragma unroll
    for (int j = 0; j < INC; ++j) ax[j] = 0.0f;
    int s = start[node], t = start[node + 1];
    for (int k = s + sub; k < t; k += 4) {
        unsigned int src = edges[k];
        float n = F[DIS_O + src] * dn;
        const float2* xr = (const float2*)(F + XF_O + (long)src * INC);
#pragma unroll
        for (int j = 0; j < 5; ++j) {
            float2 v = xr[j];
            ax[2 * j]     = fmaf(n, v.x, ax[2 * j]);
            ax[2 * j + 1] = fmaf(n, v.y, ax[2 * j + 1]);
        }
    }
    if (sub == 0) {   // self-loop once
        float dd = dn * dn;
        const float2* xr = (const float2*)(F + XF_O + (long)node * INC);
#pragma unroll
        for (int j = 0; j < 5; ++j) {
            float2 v = xr[j];
            ax[2 * j]     = fmaf(dd, v.x, ax[2 * j]);
            ax[2 * j + 1] = fmaf(dd, v.y, ax[2 * j + 1]);
        }
    }
    // quad butterfly (quads are wave-aligned: masks 1,2 stay inside the quad)
#pragma unroll
    for (int j = 0; j < INC; ++j) {
        ax[j] += __shfl_xor(ax[j], 1, 64);
        ax[j] += __shfl_xor(ax[j], 2, 64);
    }
    // this thread emits features [sub*24, sub*24+24)
    int f0 = sub * 24;
    unsigned int* hrow = (unsigned int*)(h + (size_t)node * HID);
#pragma unroll
    for (int f = f0; f < f0 + 24; f += 2) {
        float a0 = w1s[960 + f], a1 = w1s[960 + f + 1];
#pragma unroll
        for (int kk = 0; kk < INC; ++kk) {
            a0 = fmaf(ax[kk], w1s[kk * HID + f], a0);
            a1 = fmaf(ax[kk], w1s[kk * HID + f + 1], a1);
        }
        a0 = fmaxf(a0, 0.0f); a1 = fmaxf(a1, 0.0f);
        unsigned int u0 = f2bu(a0), u1 = f2bu(a1);
        hrow[f >> 1] = u0 | (u1 << 16);
    }
}

// K5: pure gather-aggregate — one wave per node, lanes 0..47 hold feature
// pairs (2L,2L+1). Edge records + dis[src] are wave-uniform scalar loads;
// only the h-row reads are vector traffic. Writes v as packed bf16.
__global__ __launch_bounds__(256) void k_gaggh(const int* start, const unsigned int* edges,
                                               const float* F, const unsigned short* h,
                                               unsigned int* v) {
    int wid = threadIdx.x >> 6;
    int lane = threadIdx.x & 63;
    int node = blockIdx.x * 4 + wid;
    if (lane >= 48) return;
    const unsigned int* hb = (const unsigned int*)h;
    float dn = F[DIS_O + node];

    int s = start[node], t = start[node + 1];
    float a0 = 0.0f, a1 = 0.0f;
    int k = s;
    for (; k + 7 < t; k += 8) {
        unsigned int s0 = edges[k],     s1 = edges[k + 1], s2 = edges[k + 2], s3 = edges[k + 3];
        unsigned int s4 = edges[k + 4], s5 = edges[k + 5], s6 = edges[k + 6], s7 = edges[k + 7];
        unsigned int p0 = hb[(size_t)s0 * 48 + lane];
        unsigned int p1 = hb[(size_t)s1 * 48 + lane];
        unsigned int p2 = hb[(size_t)s2 * 48 + lane];
        unsigned int p3 = hb[(size_t)s3 * 48 + lane];
        unsigned int p4 = hb[(size_t)s4 * 48 + lane];
        unsigned int p5 = hb[(size_t)s5 * 48 + lane];
        unsigned int p6 = hb[(size_t)s6 * 48 + lane];
        unsigned int p7 = hb[(size_t)s7 * 48 + lane];
        float n0 = F[DIS_O + s0] * dn, n1 = F[DIS_O + s1] * dn;
        float n2 = F[DIS_O + s2] * dn, n3 = F[DIS_O + s3] * dn;
        float n4 = F[DIS_O + s4] * dn, n5 = F[DIS_O + s5] * dn;
        float n6 = F[DIS_O + s6] * dn, n7 = F[DIS_O + s7] * dn;
        a0 = fmaf(n0, bfLo(p0), a0); a1 = fmaf(n0, bfHi(p0), a1);
        a0 = fmaf(n1, bfLo(p1), a0); a1 = fmaf(n1, bfHi(p1), a1);
        a0 = fmaf(n2, bfLo(p2), a0); a1 = fmaf(n2, bfHi(p2), a1);
        a0 = fmaf(n3, bfLo(p3), a0); a1 = fmaf(n3, bfHi(p3), a1);
        a0 = fmaf(n4, bfLo(p4), a0); a1 = fmaf(n4, bfHi(p4), a1);
        a0 = fmaf(n5, bfLo(p5), a0); a1 = fmaf(n5, bfHi(p5), a1);
        a0 = fmaf(n6, bfLo(p6), a0); a1 = fmaf(n6, bfHi(p6), a1);
        a0 = fmaf(n7, bfLo(p7), a0); a1 = fmaf(n7, bfHi(p7), a1);
    }
    for (; k < t; ++k) {
        unsigned int s0 = edges[k];
        unsigned int p0 = hb[(size_t)s0 * 48 + lane];
        float n0 = F[DIS_O + s0] * dn;
        a0 = fmaf(n0, bfLo(p0), a0); a1 = fmaf(n0, bfHi(p0), a1);
    }
    float dd = dn * dn;
    unsigned int ps = hb[(size_t)node * 48 + lane];
    a0 = fmaf(dd, bfLo(ps), a0); a1 = fmaf(dd, bfHi(ps), a1);
    v[(size_t)node * 48 + lane] = (unsigned int)f2bu(a0) | ((unsigned int)f2bu(a1) << 16);
}

// K6: MFMA head GEMM — v[50000,96]bf16 @ WcatT^T + bias -> d_out.
// One wave per 16-row M-tile, 6 N-tiles, K=96 (3 MFMA each).
__global__ __launch_bounds__(256) void k_heads(const unsigned short* v, const unsigned short* wct,
                                               const float* F, const int* flags, void* dout) {
    int wid = threadIdx.x >> 6;
    int lane = threadIdx.x & 63;
    int mtile = blockIdx.x * 4 + wid;
    if (mtile >= MTILES) return;
    int l16 = lane & 15, quad = lane >> 4;

    const unsigned short* vb = v + ((size_t)mtile * 16 + l16) * HID + quad * 8;
    short8 afr0 = *(const short8*)(vb);
    short8 afr1 = *(const short8*)(vb + 32);
    short8 afr2 = *(const short8*)(vb + 64);

    int ff = flags[1];
#pragma unroll
    for (int nt = 0; nt < 6; ++nt) {
        const unsigned short* wb = wct + ((size_t)nt * 16 + l16) * HID + quad * 8;
        short8 b0 = *(const short8*)(wb);
        short8 b1 = *(const short8*)(wb + 32);
        short8 b2 = *(const short8*)(wb + 64);
        f32x4 acc = {0.0f, 0.0f, 0.0f, 0.0f};
        acc = __builtin_amdgcn_mfma_f32_16x16x32_bf16(afr0, b0, acc, 0, 0, 0);
        acc = __builtin_amdgcn_mfma_f32_16x16x32_bf16(afr1, b1, acc, 0, 0, 0);
        acc = __builtin_amdgcn_mfma_f32_16x16x32_bf16(afr2, b2, acc, 0, 0, 0);
        int n = nt * 16 + l16;                 // 0..95: <48 mu, >=48 logstd
        float bias = (n < OUTC) ? F[BMF_O + n] : F[BLF_O + n - OUTC];
        long obase = (n < OUTC) ? ((long)n) : (NOUT + (long)(n - OUTC));
#pragma unroll
        for (int r = 0; r < 4; ++r) {
            int m = mtile * 16 + quad * 4 + r;
            float val = acc[r] + bias;
            long oi = (long)m * OUTC + obase;
            if (ff) ((float*)dout)[oi] = val;
            else    ((bf16*)dout)[oi] = __float2bfloat16(val);
        }
    }
}

extern "C" void kernel_launch(void* const* d_in, const int* in_sizes, int n_in,
                              void* d_out, int out_size, void* d_ws, size_t ws_size,
                              hipStream_t stream) {
    const int* ei = (const int*)d_in[1];
    int* flags = (int*)d_ws;
    float* F = (float*)((char*)d_ws + 16);
    unsigned short* h   = (unsigned short*)((char*)d_ws + 16 + FLOATS_TOT * 4);
    unsigned short* wct = h + (size_t)NND * HID;
    unsigned short* vv  = wct + (size_t)HID * HID;
    int* intBase = (int*)(vv + (size_t)NND * HID);
    int* cnt    = intBase + CNT_IO;
    int* start  = intBase + START_IO;
    int* cursor = intBase + CUR_IO;
    int* bsum   = intBase + BS_IO;
    int* boff   = intBase + BOFF_IO;
    unsigned int* pk    = (unsigned int*)(intBase + PK_IO);
    unsigned int* edges = (unsigned int*)(intBase + EDGE_IO);

    hipMemsetAsync(cnt, 0, NND * 4, stream);

    k_sniff<<<1, 256, 0, stream>>>(ei, (const unsigned short*)d_in[0], flags);
    k_prep<<<(CVT_TOT + DEG_THREADS + 255) / 256, 256, 0, stream>>>(
        d_in[0], d_in[2], d_in[3], d_in[4], d_in[5], d_in[6], d_in[7], ei, flags, F, wct, pk, cnt);
    k_bsum<<<NBLK, 256, 0, stream>>>(cnt, bsum);
    k_scan2<<<1, 256, 0, stream>>>(bsum, boff);
    k_fill<<<NBLK, 256, 0, stream>>>(cnt, boff, start, cursor, F);
    k_scatter<<<NPART * SCAT_BPP, 256, 0, stream>>>(pk, cursor, edges);
    k_layer1<<<(NND * 4 + 255) / 256, 256, 0, stream>>>(start, edges, F, h);
    k_gaggh<<<NND / 4, 256, 0, stream>>>(start, edges, F, h, (unsigned int*)vv);
    k_heads<<<(MTILES + 3) / 4, 256, 0, stream>>>(vv, wct, F, flags, d_out);
}

// Round 8
// 238.151 us; speedup vs baseline: 1.0061x; 1.0061x over previous
//
#include <hip/hip_runtime.h>
#include <hip/hip_bf16.h>

// Problem constants
#define NND 50000      // nodes
#define NED 800000     // edges (without self-loops)
#define INC 10
#define HID 96
#define OUTC 48
#define NOUT (NND*OUTC)
#define NBLK 196       // ceil(NND/256)
#define MTILES 3125    // 50000 / 16
#define NPART 8        // XCD partitions for the scatter
#define PART_NODES 6250
#define SCAT_BPP 64    // blocks per partition

typedef __hip_bfloat16 bf16;
typedef __attribute__((ext_vector_type(8))) short short8;
typedef __attribute__((ext_vector_type(4))) float f32x4;

// ---- workspace layout ----
// [0,16): flags (written by k_prep block 0, read by k_heads).
// Float region (offsets in floats from F):
#define XF_O   0L                 // 500000  (x: N x 10)
#define W1F_O  500000L            // 960   (W1 then b1 contiguous: 1056)
#define B1F_O  500960L            // 96
#define WMF_O  501056L            // 4608  (fp32 copy; heads use bf16 wct)
#define BMF_O  505664L            // 48
#define WLF_O  505712L            // 4608
#define BLF_O  510320L            // 48
#define DIS_O  510368L            // 50000 (rsqrt(deg+1))
#define FLOATS_TOT 560368L
// after floats: h   [NND*96] ushort (bf16)
//               wct [96*96]  ushort (bf16) WcatT[n][k]; n<48 W_mu col, n>=48 W_ls col
//               v   [NND*96] ushort (bf16) aggregated hidden
// int region after v (intBase is 16B-aligned):
#define CNT_IO   0L               // 50000
#define START_IO 50000L           // 50001 (+1 pad -> 100002)
#define CUR_IO   100002L          // 50000
#define BS_IO    150002L          // 256
#define BOFF_IO  150258L          // 256 + pad -> 150528 (16B aligned)
#define PK_IO    150528L          // 800000 u32 packed {row | col<<16}
#define EDGE_IO  950528L          // 800000 int2 {src, bitcast fp32 norm}

__device__ __forceinline__ float b2f(bf16 v) { return __bfloat162float(v); }
__device__ __forceinline__ float bfLo(unsigned int p) { return __uint_as_float(p << 16); }
__device__ __forceinline__ float bfHi(unsigned int p) { return __uint_as_float(p & 0xffff0000u); }
__device__ __forceinline__ unsigned short f2bu(float v) {
    return __bfloat16_as_ushort(__float2bfloat16(v));
}

// K1: fused dtype-sniff (block-local) + convert-to-fp32 + bf16 transposed
//     head-weight build + edge pack (row|col<<16) + degree count
#define CVT_TOT 510368
#define DEG_THREADS 200000
__global__ __launch_bounds__(256) void k_prep(const void* x, const void* w1, const void* b1,
                                              const void* wm, const void* bm,
                                              const void* wl, const void* bl,
                                              const int* ei, int* flags,
                                              float* F, unsigned short* wct,
                                              unsigned int* pk, int* cnt) {
    // --- block-local sniff (every block; ~5 KB of L2-hot reads) ---
    __shared__ int s_oddnz, s_big;
    if (threadIdx.x == 0) { s_oddnz = 0; s_big = 0; }
    __syncthreads();
    {
        int t = threadIdx.x;
        if (t < 128) {
            if (ei[2 * t + 1] != 0) atomicOr(&s_oddnz, 1);
        }
        const unsigned short* xs = (const unsigned short*)x;
        unsigned short u = xs[t * 8];          // sample 1 of 8 (256 samples is plenty)
        float f = __uint_as_float(((unsigned int)u) << 16);
        int big = !(fabsf(f) < 64.0f);
        unsigned short u2 = xs[t * 8 + 5];
        float f2 = __uint_as_float(((unsigned int)u2) << 16);
        big |= !(fabsf(f2) < 64.0f);
        if (big) atomicOr(&s_big, 1);
    }
    __syncthreads();
    int iw = (s_oddnz == 0) ? 1 : 0;   // 1 = int64 edge_index
    int ff = s_big ? 1 : 0;            // 1 = fp32 floats
    if (blockIdx.x == 0 && threadIdx.x == 0) { flags[0] = iw; flags[1] = ff; }

    int idx = blockIdx.x * 256 + threadIdx.x;
    if (idx < CVT_TOT) {
        const void* src; long off;
        if      (idx < 500000) { src = x;  off = idx; }
        else if (idx < 500960) { src = w1; off = idx - 500000; }
        else if (idx < 501056) { src = b1; off = idx - 500960; }
        else if (idx < 505664) { src = wm; off = idx - 501056; }
        else if (idx < 505712) { src = bm; off = idx - 505664; }
        else if (idx < 510320) { src = wl; off = idx - 505712; }
        else                   { src = bl; off = idx - 510320; }
        float v = ff ? ((const float*)src)[off] : b2f(((const bf16*)src)[off]);
        F[idx] = v;
        if (idx >= 501056 && idx < 505664) {          // W_mu[k][j] -> wct[j][k]
            long rel = idx - 501056;
            wct[(rel % OUTC) * (long)HID + rel / OUTC] = f2bu(v);
        } else if (idx >= 505712 && idx < 510320) {   // W_ls[k][j] -> wct[48+j][k]
            long rel = idx - 505712;
            wct[(OUTC + rel % OUTC) * (long)HID + rel / OUTC] = f2bu(v);
        }
    } else if (idx < CVT_TOT + DEG_THREADS) {
        int j = idx - CVT_TOT;   // 4 edges per thread
        int r0, r1, r2, r3, c0, c1, c2, c3;
        if (iw) {
            const int4* pr = (const int4*)ei;
            const int4* pc = (const int4*)(ei + 2L * NED);
            int4 ra = pr[2 * j], rb = pr[2 * j + 1];
            int4 ca = pc[2 * j], cb = pc[2 * j + 1];
            r0 = ra.x; r1 = ra.z; r2 = rb.x; r3 = rb.z;
            c0 = ca.x; c1 = ca.z; c2 = cb.x; c3 = cb.z;
        } else {
            int4 ra = ((const int4*)ei)[j];
            int4 ca = ((const int4*)(ei + NED))[j];
            r0 = ra.x; r1 = ra.y; r2 = ra.z; r3 = ra.w;
            c0 = ca.x; c1 = ca.y; c2 = ca.z; c3 = ca.w;
        }
        uint4 out;
        out.x = (unsigned)r0 | ((unsigned)c0 << 16);
        out.y = (unsigned)r1 | ((unsigned)c1 << 16);
        out.z = (unsigned)r2 | ((unsigned)c2 << 16);
        out.w = (unsigned)r3 | ((unsigned)c3 << 16);
        ((uint4*)pk)[j] = out;
        atomicAdd(&cnt[c0], 1); atomicAdd(&cnt[c1], 1);
        atomicAdd(&cnt[c2], 1); atomicAdd(&cnt[c3], 1);
    }
}

// K2a: per-block sums of cnt (wave shuffle reduce)
__global__ __launch_bounds__(256) void k_bsum(const int* cnt, int* bsum) {
    int i = blockIdx.x * 256 + threadIdx.x;
    int v = (i < NND) ? cnt[i] : 0;
#pragma unroll
    for (int off = 32; off >= 1; off >>= 1) v += __shfl_down(v, off, 64);
    __shared__ int ws[4];
    int wid = threadIdx.x >> 6, lane = threadIdx.x & 63;
    if (lane == 0) ws[wid] = v;
    __syncthreads();
    if (threadIdx.x == 0) bsum[blockIdx.x] = ws[0] + ws[1] + ws[2] + ws[3];
}

// K2b: single small block scans the 196 block sums -> exclusive offsets
__global__ __launch_bounds__(256) void k_scan2(const int* bsum, int* boff) {
    __shared__ int lds[256];
    int tid = threadIdx.x;
    int v = (tid < NBLK) ? bsum[tid] : 0;
    lds[tid] = v;
    __syncthreads();
    int incl = v;
    for (int off = 1; off < 256; off <<= 1) {
        int t = (tid >= off) ? lds[tid - off] : 0;
        __syncthreads();
        incl += t; lds[tid] = incl;
        __syncthreads();
    }
    if (tid < NBLK) boff[tid] = incl - v;
}

// K2c: block-local exclusive scan + offset -> start/cursor; dis=rsqrt(deg+1)
__global__ __launch_bounds__(256) void k_fill(const int* cnt, const int* boff,
                                              int* start, int* cursor, float* F) {
    __shared__ int lds[256];
    int tid = threadIdx.x;
    int i = blockIdx.x * 256 + tid;
    int c = (i < NND) ? cnt[i] : 0;
    lds[tid] = c;
    __syncthreads();
    int incl = c;
    for (int off = 1; off < 256; off <<= 1) {
        int t = (tid >= off) ? lds[tid - off] : 0;
        __syncthreads();
        incl += t; lds[tid] = incl;
        __syncthreads();
    }
    int run = boff[blockIdx.x] + incl - c;
    if (i <= NND) start[i] = run;        // i==NND lands here -> total == NED
    if (i < NND) {
        cursor[i] = run;
        F[DIS_O + i] = rsqrtf((float)c + 1.0f);
    }
}

// K3: XCD-partitioned scatter. Block b owns dest range [ (b&7)*6250, +6250 ).
// 64 blocks/partition sweep the packed stream; only in-range edges commit
// -> every edges[]/cursor[] line written by ONE XCD. Records carry fp32 norm
// so consumers have a single-load edge body (no dependent dis chain).
__global__ __launch_bounds__(256) void k_scatter(const unsigned int* pk, const float* F,
                                                 int* cursor, int2* edges) {
    int p = blockIdx.x & (NPART - 1);
    int bi = blockIdx.x >> 3;                 // 0..63
    unsigned int lo = (unsigned)p * PART_NODES;
    int tid = bi * 256 + threadIdx.x;         // 0..16383
    const uint4* pk4 = (const uint4*)pk;
    for (int g = tid; g < NED / 4; g += SCAT_BPP * 256) {
        uint4 e = pk4[g];
#pragma unroll
        for (int q = 0; q < 4; ++q) {
            unsigned int w = (q == 0) ? e.x : (q == 1) ? e.y : (q == 2) ? e.z : e.w;
            unsigned int c = w >> 16;
            if (c - lo < PART_NODES) {
                unsigned int r = w & 0xffffu;
                int pos = atomicAdd(&cursor[c], 1);
                float nrm = F[DIS_O + r] * F[DIS_O + c];
                edges[pos] = make_int2((int)r, __float_as_int(nrm));
            }
        }
    }
}

// K4: fused layer1 — FOUR threads per node (quad in-wave): each takes every
// 4th edge, butterfly-combines the 10 partials, then emits 24 of 96 h feats.
__global__ __launch_bounds__(256) void k_layer1(const int* start, const int2* edges,
                                                const float* F, unsigned short* h) {
    __shared__ float w1s[1056];   // W1 (960) then b1 (96), contiguous in F
    for (int i = threadIdx.x; i < 1056; i += 256) w1s[i] = F[W1F_O + i];
    __syncthreads();
    int idx = blockIdx.x * 256 + threadIdx.x;
    if (idx >= NND * 4) return;
    int node = idx >> 2, sub = idx & 3;
    float ax[INC];
#pragma unroll
    for (int j = 0; j < INC; ++j) ax[j] = 0.0f;
    int s = start[node], t = start[node + 1];
    for (int k = s + sub; k < t; k += 4) {
        int2 rec = edges[k];
        float n = __int_as_float(rec.y);
        const float2* xr = (const float2*)(F + XF_O + (long)rec.x * INC);
#pragma unroll
        for (int j = 0; j < 5; ++j) {
            float2 v = xr[j];
            ax[2 * j]     = fmaf(n, v.x, ax[2 * j]);
            ax[2 * j + 1] = fmaf(n, v.y, ax[2 * j + 1]);
        }
    }
    if (sub == 0) {   // self-loop once
        float d = F[DIS_O + node]; float dd = d * d;
        const float2* xr = (const float2*)(F + XF_O + (long)node * INC);
#pragma unroll
        for (int j = 0; j < 5; ++j) {
            float2 v = xr[j];
            ax[2 * j]     = fmaf(dd, v.x, ax[2 * j]);
            ax[2 * j + 1] = fmaf(dd, v.y, ax[2 * j + 1]);
        }
    }
    // quad butterfly (quads are wave-aligned: masks 1,2 stay inside the quad)
#pragma unroll
    for (int j = 0; j < INC; ++j) {
        ax[j] += __shfl_xor(ax[j], 1, 64);
        ax[j] += __shfl_xor(ax[j], 2, 64);
    }
    // this thread emits features [sub*24, sub*24+24)
    int f0 = sub * 24;
    unsigned int* hrow = (unsigned int*)(h + (size_t)node * HID);
#pragma unroll
    for (int f = f0; f < f0 + 24; f += 2) {
        float a0 = w1s[960 + f], a1 = w1s[960 + f + 1];
#pragma unroll
        for (int kk = 0; kk < INC; ++kk) {
            a0 = fmaf(ax[kk], w1s[kk * HID + f], a0);
            a1 = fmaf(ax[kk], w1s[kk * HID + f + 1], a1);
        }
        a0 = fmaxf(a0, 0.0f); a1 = fmaxf(a1, 0.0f);
        unsigned int u0 = f2bu(a0), u1 = f2bu(a1);
        hrow[f >> 1] = u0 | (u1 << 16);
    }
}

// K5: pure gather-aggregate — one wave per node, lanes 0..47 hold feature
// pairs (2L,2L+1), 8-edge unroll, self-loop, write v as packed bf16.
// Single-load edge body: norm rides in the record.
__global__ __launch_bounds__(256) void k_gaggh(const int* start, const int2* edges,
                                               const float* F, const unsigned short* h,
                                               unsigned int* v) {
    int wid = threadIdx.x >> 6;
    int lane = threadIdx.x & 63;
    int node = blockIdx.x * 4 + wid;
    if (lane >= 48) return;
    const unsigned int* hb = (const unsigned int*)h;

    int s = start[node], t = start[node + 1];
    float a0 = 0.0f, a1 = 0.0f;
    int k = s;
    for (; k + 7 < t; k += 8) {
        int2 e0 = edges[k],     e1 = edges[k + 1], e2 = edges[k + 2], e3 = edges[k + 3];
        int2 e4 = edges[k + 4], e5 = edges[k + 5], e6 = edges[k + 6], e7 = edges[k + 7];
        unsigned int p0 = hb[(size_t)e0.x * 48 + lane];
        unsigned int p1 = hb[(size_t)e1.x * 48 + lane];
        unsigned int p2 = hb[(size_t)e2.x * 48 + lane];
        unsigned int p3 = hb[(size_t)e3.x * 48 + lane];
        unsigned int p4 = hb[(size_t)e4.x * 48 + lane];
        unsigned int p5 = hb[(size_t)e5.x * 48 + lane];
        unsigned int p6 = hb[(size_t)e6.x * 48 + lane];
        unsigned int p7 = hb[(size_t)e7.x * 48 + lane];
        a0 = fmaf(__int_as_float(e0.y), bfLo(p0), a0); a1 = fmaf(__int_as_float(e0.y), bfHi(p0), a1);
        a0 = fmaf(__int_as_float(e1.y), bfLo(p1), a0); a1 = fmaf(__int_as_float(e1.y), bfHi(p1), a1);
        a0 = fmaf(__int_as_float(e2.y), bfLo(p2), a0); a1 = fmaf(__int_as_float(e2.y), bfHi(p2), a1);
        a0 = fmaf(__int_as_float(e3.y), bfLo(p3), a0); a1 = fmaf(__int_as_float(e3.y), bfHi(p3), a1);
        a0 = fmaf(__int_as_float(e4.y), bfLo(p4), a0); a1 = fmaf(__int_as_float(e4.y), bfHi(p4), a1);
        a0 = fmaf(__int_as_float(e5.y), bfLo(p5), a0); a1 = fmaf(__int_as_float(e5.y), bfHi(p5), a1);
        a0 = fmaf(__int_as_float(e6.y), bfLo(p6), a0); a1 = fmaf(__int_as_float(e6.y), bfHi(p6), a1);
        a0 = fmaf(__int_as_float(e7.y), bfLo(p7), a0); a1 = fmaf(__int_as_float(e7.y), bfHi(p7), a1);
    }
    for (; k < t; ++k) {
        int2 e0 = edges[k];
        unsigned int p0 = hb[(size_t)e0.x * 48 + lane];
        a0 = fmaf(__int_as_float(e0.y), bfLo(p0), a0); a1 = fmaf(__int_as_float(e0.y), bfHi(p0), a1);
    }
    float d = F[DIS_O + node]; float dd = d * d;
    unsigned int ps = hb[(size_t)node * 48 + lane];
    a0 = fmaf(dd, bfLo(ps), a0); a1 = fmaf(dd, bfHi(ps), a1);
    v[(size_t)node * 48 + lane] = (unsigned int)f2bu(a0) | ((unsigned int)f2bu(a1) << 16);
}

// K6: MFMA head GEMM — v[50000,96]bf16 @ WcatT^T + bias -> d_out.
// One wave per 16-row M-tile, 6 N-tiles, K=96 (3 MFMA each).
__global__ __launch_bounds__(256) void k_heads(const unsigned short* v, const unsigned short* wct,
                                               const float* F, const int* flags, void* dout) {
    int wid = threadIdx.x >> 6;
    int lane = threadIdx.x & 63;
    int mtile = blockIdx.x * 4 + wid;
    if (mtile >= MTILES) return;
    int l16 = lane & 15, quad = lane >> 4;

    const unsigned short* vb = v + ((size_t)mtile * 16 + l16) * HID + quad * 8;
    short8 afr0 = *(const short8*)(vb);
    short8 afr1 = *(const short8*)(vb + 32);
    short8 afr2 = *(const short8*)(vb + 64);

    int ff = flags[1];
#pragma unroll
    for (int nt = 0; nt < 6; ++nt) {
        const unsigned short* wb = wct + ((size_t)nt * 16 + l16) * HID + quad * 8;
        short8 b0 = *(const short8*)(wb);
        short8 b1 = *(const short8*)(wb + 32);
        short8 b2 = *(const short8*)(wb + 64);
        f32x4 acc = {0.0f, 0.0f, 0.0f, 0.0f};
        acc = __builtin_amdgcn_mfma_f32_16x16x32_bf16(afr0, b0, acc, 0, 0, 0);
        acc = __builtin_amdgcn_mfma_f32_16x16x32_bf16(afr1, b1, acc, 0, 0, 0);
        acc = __builtin_amdgcn_mfma_f32_16x16x32_bf16(afr2, b2, acc, 0, 0, 0);
        int n = nt * 16 + l16;                 // 0..95: <48 mu, >=48 logstd
        float bias = (n < OUTC) ? F[BMF_O + n] : F[BLF_O + n - OUTC];
        long obase = (n < OUTC) ? ((long)n) : (NOUT + (long)(n - OUTC));
#pragma unroll
        for (int r = 0; r < 4; ++r) {
            int m = mtile * 16 + quad * 4 + r;
            float val = acc[r] + bias;
            long oi = (long)m * OUTC + obase;
            if (ff) ((float*)dout)[oi] = val;
            else    ((bf16*)dout)[oi] = __float2bfloat16(val);
        }
    }
}

extern "C" void kernel_launch(void* const* d_in, const int* in_sizes, int n_in,
                              void* d_out, int out_size, void* d_ws, size_t ws_size,
                              hipStream_t stream) {
    const int* ei = (const int*)d_in[1];
    int* flags = (int*)d_ws;
    float* F = (float*)((char*)d_ws + 16);
    unsigned short* h   = (unsigned short*)((char*)d_ws + 16 + FLOATS_TOT * 4);
    unsigned short* wct = h + (size_t)NND * HID;
    unsigned short* vv  = wct + (size_t)HID * HID;
    int* intBase = (int*)(vv + (size_t)NND * HID);
    int* cnt    = intBase + CNT_IO;
    int* start  = intBase + START_IO;
    int* cursor = intBase + CUR_IO;
    int* bsum   = intBase + BS_IO;
    int* boff   = intBase + BOFF_IO;
    unsigned int* pk = (unsigned int*)(intBase + PK_IO);
    int2* edges      = (int2*)(intBase + EDGE_IO);

    hipMemsetAsync(cnt, 0, NND * 4, stream);

    k_prep<<<(CVT_TOT + DEG_THREADS + 255) / 256, 256, 0, stream>>>(
        d_in[0], d_in[2], d_in[3], d_in[4], d_in[5], d_in[6], d_in[7], ei, flags, F, wct, pk, cnt);
    k_bsum<<<NBLK, 256, 0, stream>>>(cnt, bsum);
    k_scan2<<<1, 256, 0, stream>>>(bsum, boff);
    k_fill<<<NBLK, 256, 0, stream>>>(cnt, boff, start, cursor, F);
    k_scatter<<<NPART * SCAT_BPP, 256, 0, stream>>>(pk, F, cursor, edges);
    k_layer1<<<(NND * 4 + 255) / 256, 256, 0, stream>>>(start, edges, F, h);
    k_gaggh<<<NND / 4, 256, 0, stream>>>(start, edges, F, h, (unsigned int*)vv);
    k_heads<<<(MTILES + 3) / 4, 256, 0, stream>>>(vv, wct, F, flags, d_out);
}